// Round 8
// baseline (316.175 us; speedup 1.0000x reference)
//
#include <hip/hip_runtime.h>
#include <hip/hip_cooperative_groups.h>

namespace cg = cooperative_groups;

#define TI   64     // tile edge
#define BT   256    // threads per block (4 waves)
#define GRID 1536   // 6 blocks/CU x 256 CU: co-resident with margin

// branchless bell; NaN (sentinel self-pair: 0*inf) fails ordered compares -> 0
__device__ __forceinline__ float bell(float d, float s) {
    float r  = d * __builtin_amdgcn_rcpf(s);
    float nr = fmaf(-2.0f * r, r, 1.0f);
    float t  = r - 1.0f;
    float fr = (t + t) * t;
    float p  = (r <= 0.5f) ? nr : fr;
    return (r <= 1.0f) ? p : 0.0f;
}

__device__ __forceinline__ float term(float4 P, float pai, float4 q) {
    float px = bell(fabsf(P.x - q.x), P.z + q.z);
    float py = bell(fabsf(P.y - q.y), P.w + q.w);
    return fmaf(pai, 1.0f, q.z * q.w) * px * py;   // (pai + aq) * px * py
}

__device__ __forceinline__ int tri_off(int ti, int T) {
    return ti * T - (ti * (ti - 1)) / 2;
}

__global__ __launch_bounds__(BT, 6) void fused_kernel(
    const float* __restrict__ pos,
    const float* __restrict__ msx, const float* __restrict__ msy,
    const float* __restrict__ bpx, const float* __restrict__ bpy,
    const int*   __restrict__ midx,
    int num_nodes, int m, int N, int Npad, int T, int nblk, int nprep,
    float4* __restrict__ p4, float* __restrict__ t_part,
    float* __restrict__ partials, float* __restrict__ out)
{
    cg::grid_group gg = cg::this_grid();
    const int tid = threadIdx.x, bid = blockIdx.x;
    const int lane = tid & 63, wid = tid >> 6;
    __shared__ float4 qs[TI];
    __shared__ float  wred[BT / 64];

    // ---------- phase 1: prep (blocks [0, nprep)) ----------
    if (bid < nprep) {
        const int g = bid * BT + tid;
        const bool is64 = (midx[1] == 0) && (midx[3] == 0) && (midx[5] == 0);
        float a = 0.0f, xi = 1e18f, yi = 1e18f, hx = 0.0f, hy = 0.0f;
        if (g < N) {
            hx = 0.5f * msx[g];
            hy = 0.5f * msy[g];
            if (g < m) {
                int id = is64 ? midx[2 * g] : midx[g];
                xi = pos[id]             + hx;
                yi = pos[num_nodes + id] + hy;
            } else {
                xi = bpx[g - m];
                yi = bpy[g - m];
            }
            a = 4.0f * hx * hy;           // true area
        }
        if (g < Npad) p4[g] = make_float4(xi, yi, hx, hy);
        for (int off = 32; off > 0; off >>= 1) a += __shfl_down(a, off, 64);
        if (lane == 0) wred[wid] = a;
        __syncthreads();
        if (tid == 0)
            t_part[bid] = wred[0] + wred[1] + wred[2] + wred[3];
    }
    gg.sync();

    // ---------- phase 2: triangular tile-pairs, grid-stride ----------
    float po = 0.0f, pd = 0.0f;        // off-diag / diag accumulators
    for (int b = bid; b < nblk; b += GRID) {
        const int w2 = 2 * T + 1;
        int ti = (int)(((float)w2 - sqrtf((float)(w2 * w2 - 8 * b))) * 0.5f);
        if (ti > T - 1) ti = T - 1;
        while (ti > 0 && tri_off(ti, T) > b) --ti;
        while (tri_off(ti + 1, T) <= b) ++ti;
        const int tj = ti + (b - tri_off(ti, T));

        __syncthreads();               // all waves done reading previous qs
        if (tid < TI) qs[tid] = p4[tj * TI + tid];
        __syncthreads();

        const float4 P = p4[ti * TI + lane];
        const float pai = P.z * P.w;   // quarter-area
        float a0 = 0.0f, a1 = 0.0f;
        #pragma unroll
        for (int k = 0; k < 16; k += 2) {
            a0 += term(P, pai, qs[wid * 16 + k]);
            a1 += term(P, pai, qs[wid * 16 + k + 1]);
        }
        float acc = a0 + a1;
        if (ti == tj) pd += acc; else po += acc;
    }
    float part = fmaf(0.5f, pd, po);
    for (int off = 32; off > 0; off >>= 1) part += __shfl_down(part, off, 64);
    __syncthreads();                   // phase-1/loop wred reads done
    if (lane == 0) wred[wid] = part;
    __syncthreads();
    if (tid == 0)
        partials[bid] = wred[0] + wred[1] + wred[2] + wred[3];
    gg.sync();

    // ---------- phase 3: final reduction (block 0) ----------
    if (bid == 0) {
        float s = 0.0f;
        for (int i = tid; i < GRID; i += BT) s += partials[i];
        float t = (tid < nprep) ? t_part[tid] : 0.0f;
        for (int off = 32; off > 0; off >>= 1) {
            s += __shfl_down(s, off, 64);
            t += __shfl_down(t, off, 64);
        }
        __shared__ float ws2[BT / 64], wt2[BT / 64];
        if (lane == 0) { ws2[wid] = s; wt2[wid] = t; }
        __syncthreads();
        if (tid == 0) {
            float S  = ws2[0] + ws2[1] + ws2[2] + ws2[3];
            float Tt = wt2[0] + wt2[1] + wt2[2] + wt2[3];
            // quarter-area scale: triu = 4*S - Tt
            float l = (4.0f * S - Tt) / Tt;
            out[0] = l * l;
        }
    }
}

// ---------- fallback path (non-cooperative), proven in R7 ----------
__global__ __launch_bounds__(256) void prep_kernel(
    const float* __restrict__ pos,
    const float* __restrict__ msx, const float* __restrict__ msy,
    const float* __restrict__ bpx, const float* __restrict__ bpy,
    const int*   __restrict__ midx,
    int num_nodes, int m, int N, int Npad,
    float4* __restrict__ p4, float* __restrict__ t_part)
{
    const int i = blockIdx.x * 256 + threadIdx.x;
    const bool is64 = (midx[1] == 0) && (midx[3] == 0) && (midx[5] == 0);
    float a = 0.0f, xi = 1e18f, yi = 1e18f, hx = 0.0f, hy = 0.0f;
    if (i < N) {
        hx = 0.5f * msx[i];
        hy = 0.5f * msy[i];
        if (i < m) {
            int id = is64 ? midx[2 * i] : midx[i];
            xi = pos[id]             + hx;
            yi = pos[num_nodes + id] + hy;
        } else {
            xi = bpx[i - m];
            yi = bpy[i - m];
        }
        a = 4.0f * hx * hy;
    }
    if (i < Npad) p4[i] = make_float4(xi, yi, hx, hy);
    for (int off = 32; off > 0; off >>= 1) a += __shfl_down(a, off, 64);
    __shared__ float wpart[4];
    const int lane = threadIdx.x & 63, wid = threadIdx.x >> 6;
    if (lane == 0) wpart[wid] = a;
    __syncthreads();
    if (threadIdx.x == 0)
        t_part[blockIdx.x] = wpart[0] + wpart[1] + wpart[2] + wpart[3];
}

__global__ __launch_bounds__(BT) void pairs_kernel(
    const float4* __restrict__ p4, int T, float* __restrict__ partials)
{
    const int b = blockIdx.x;
    const int w = 2 * T + 1;
    int ti = (int)(((float)w - sqrtf((float)(w * w - 8 * b))) * 0.5f);
    if (ti > T - 1) ti = T - 1;
    while (ti > 0 && tri_off(ti, T) > b) --ti;
    while (tri_off(ti + 1, T) <= b) ++ti;
    const int tj = ti + (b - tri_off(ti, T));

    __shared__ float4 qs[TI];
    if (threadIdx.x < TI) qs[threadIdx.x] = p4[tj * TI + threadIdx.x];
    __syncthreads();

    const int lane = threadIdx.x & 63, wid = threadIdx.x >> 6;
    const float4 P = p4[ti * TI + lane];
    const float pai = P.z * P.w;
    float part = 0.0f;
    #pragma unroll
    for (int k = 0; k < 16; ++k)
        part += term(P, pai, qs[wid * 16 + k]);
    for (int off = 32; off > 0; off >>= 1) part += __shfl_down(part, off, 64);
    __shared__ float wsum[BT / 64];
    if (lane == 0) wsum[wid] = part;
    __syncthreads();
    if (threadIdx.x == 0) {
        float s = wsum[0] + wsum[1] + wsum[2] + wsum[3];
        partials[b] = (ti == tj) ? 0.5f * s : s;
    }
}

__global__ __launch_bounds__(256) void fin_kernel(
    const float* __restrict__ partials, int np,
    const float* __restrict__ t_part, int nt, float* __restrict__ out)
{
    float s = 0.0f;
    for (int i = threadIdx.x; i < np; i += 256) s += partials[i];
    float t = 0.0f;
    for (int i = threadIdx.x; i < nt; i += 256) t += t_part[i];
    for (int off = 32; off > 0; off >>= 1) {
        s += __shfl_down(s, off, 64);
        t += __shfl_down(t, off, 64);
    }
    __shared__ float ws[4], wt[4];
    const int lane = threadIdx.x & 63, wid = threadIdx.x >> 6;
    if (lane == 0) { ws[wid] = s; wt[wid] = t; }
    __syncthreads();
    if (threadIdx.x == 0) {
        float S = ws[0] + ws[1] + ws[2] + ws[3];
        float T = wt[0] + wt[1] + wt[2] + wt[3];
        float l = (4.0f * S - T) / T;
        out[0] = l * l;
    }
}

extern "C" void kernel_launch(void* const* d_in, const int* in_sizes, int n_in,
                              void* d_out, int out_size, void* d_ws, size_t ws_size,
                              hipStream_t stream) {
    const float* pos = (const float*)d_in[0];
    const float* msx = (const float*)d_in[1];
    const float* msy = (const float*)d_in[2];
    const float* bpx = (const float*)d_in[3];
    const float* bpy = (const float*)d_in[4];
    const int*  midx = (const int*)d_in[5];

    const int num_nodes = in_sizes[0] / 2;
    const int m  = in_sizes[5];          // 4000 movable macros
    const int nb = in_sizes[3];          // 252 boundary nodes
    const int N  = m + nb;

    const int T     = (N + TI - 1) / TI;     // 68
    const int Npad  = T * TI;                // 4352
    const int nblk  = T * (T + 1) / 2;       // 2346
    const int nprep = (Npad + BT - 1) / BT;  // 17

    float4* p4       = (float4*)d_ws;
    float*  t_part   = (float*)(p4 + Npad);
    float*  partials = t_part + nprep;       // max(GRID, nblk) floats
    float*  out      = (float*)d_out;

    void* ka[] = {
        (void*)&pos, (void*)&msx, (void*)&msy, (void*)&bpx, (void*)&bpy,
        (void*)&midx, (void*)&num_nodes, (void*)&m, (void*)&N, (void*)&Npad,
        (void*)&T, (void*)&nblk, (void*)&nprep,
        (void*)&p4, (void*)&t_part, (void*)&partials, (void*)&out
    };
    hipError_t e = hipLaunchCooperativeKernel((void*)fused_kernel,
                                              dim3(GRID), dim3(BT),
                                              ka, 0, stream);
    if (e != hipSuccess) {
        // fallback: proven 3-kernel path
        prep_kernel<<<nprep, 256, 0, stream>>>(pos, msx, msy, bpx, bpy, midx,
                                               num_nodes, m, N, Npad, p4, t_part);
        pairs_kernel<<<nblk, BT, 0, stream>>>(p4, T, partials);
        fin_kernel<<<1, 256, 0, stream>>>(partials, nblk, t_part, nprep, out);
    }
}

// Round 9
// 71.842 us; speedup vs baseline: 4.4010x; 4.4010x over previous
//
#include <hip/hip_runtime.h>

#define TI 64     // tile edge
#define BT 256    // threads per block (4 waves)

// branchless bell; NaN (sentinel self-pair: 0*inf) fails ordered compares -> 0
__device__ __forceinline__ float bell(float d, float s) {
    float r  = d * __builtin_amdgcn_rcpf(s);
    float nr = fmaf(-2.0f * r, r, 1.0f);
    float t  = r - 1.0f;
    float fr = (t + t) * t;
    float p  = (r <= 0.5f) ? nr : fr;
    return (r <= 1.0f) ? p : 0.0f;
}

__device__ __forceinline__ float term(float4 P, float pai, float4 q) {
    float px = bell(fabsf(P.x - q.x), P.z + q.z);
    float py = bell(fabsf(P.y - q.y), P.w + q.w);
    return (pai + q.z * q.w) * px * py;     // quarter-area scale
}

__device__ __forceinline__ int tri_off(int ti, int T) {
    return ti * T - (ti * (ti - 1)) / 2;    // first block index of tile-row ti
}

// prep one node g -> (x_center, y_center, hx, hy); sentinel if g >= N
__device__ __forceinline__ float4 prep_node(
    int g, int N, int m, int num_nodes, bool is64,
    const float* __restrict__ pos,
    const float* __restrict__ msx, const float* __restrict__ msy,
    const float* __restrict__ bpx, const float* __restrict__ bpy,
    const int*   __restrict__ midx)
{
    float xi = 1e18f, yi = 1e18f, hx = 0.0f, hy = 0.0f;
    if (g < N) {
        hx = 0.5f * msx[g];
        hy = 0.5f * msy[g];
        if (g < m) {
            int id = is64 ? midx[2 * g] : midx[g];
            xi = pos[id]             + hx;
            yi = pos[num_nodes + id] + hy;
        } else {
            xi = bpx[g - m];
            yi = bpy[g - m];
        }
    }
    return make_float4(xi, yi, hx, hy);
}

__global__ __launch_bounds__(BT) void fused_kernel(
    const float* __restrict__ pos,
    const float* __restrict__ msx, const float* __restrict__ msy,
    const float* __restrict__ bpx, const float* __restrict__ bpy,
    const int*   __restrict__ midx,
    int num_nodes, int m, int N, int T, int nblk,
    float* __restrict__ S_accum, float* __restrict__ T_accum,
    unsigned* __restrict__ done, float* __restrict__ out)
{
    const int tid = threadIdx.x, lane = tid & 63, wid = tid >> 6;

    // decode linear block id -> (ti, tj), ti <= tj
    const int b = blockIdx.x;
    const int w2 = 2 * T + 1;
    int ti = (int)(((float)w2 - sqrtf((float)(w2 * w2 - 8 * b))) * 0.5f);
    if (ti > T - 1) ti = T - 1;
    while (ti > 0 && tri_off(ti, T) > b) --ti;
    while (tri_off(ti + 1, T) <= b) ++ti;
    const int tj = ti + (b - tri_off(ti, T));

    // ---- in-block prep of both tiles (waves 0 and 1) ----
    __shared__ float4 qs[TI];   // j-tile
    __shared__ float4 ps[TI];   // i-tile
    // macro_idx is int64 in the reference; sorted => idx[1] >= 1, so the odd
    // int32 words are all zero iff the buffer is little-endian int64.
    const bool is64 = (midx[1] == 0) && (midx[3] == 0) && (midx[5] == 0);
    if (tid < TI) {
        qs[tid] = prep_node(tj * TI + tid, N, m, num_nodes, is64,
                            pos, msx, msy, bpx, bpy, midx);
    } else if (tid < 2 * TI) {
        ps[tid - TI] = prep_node(ti * TI + (tid - TI), N, m, num_nodes, is64,
                                 pos, msx, msy, bpx, bpy, midx);
    }
    __syncthreads();

    const float4 P = ps[lane];
    const float pai = P.z * P.w;            // quarter-area of node i

    // diagonal blocks also accumulate the tile's true area into T_accum
    if (ti == tj && wid == 0) {
        float a = 4.0f * pai;               // sentinel -> 0
        for (int off = 32; off > 0; off >>= 1) a += __shfl_down(a, off, 64);
        if (lane == 0) atomicAdd(T_accum, a);
    }

    float a0 = 0.0f, a1 = 0.0f;
    #pragma unroll
    for (int k = 0; k < 16; k += 2) {
        a0 += term(P, pai, qs[wid * 16 + k]);
        a1 += term(P, pai, qs[wid * 16 + k + 1]);
    }
    float part = a0 + a1;
    if (ti == tj) part *= 0.5f;             // diag tiles half-weight

    for (int off = 32; off > 0; off >>= 1) part += __shfl_down(part, off, 64);
    __shared__ float wred[BT / 64];
    if (lane == 0) wred[wid] = part;
    __syncthreads();

    if (tid == 0) {
        atomicAdd(S_accum, wred[0] + wred[1] + wred[2] + wred[3]);
        __threadfence();
        unsigned old = atomicAdd(done, 1u);
        if (old == (unsigned)(nblk - 1)) {  // last block: finalize
            float S  = atomicAdd(S_accum, 0.0f);   // coherent read-back
            float Tt = atomicAdd(T_accum, 0.0f);
            // quarter-area scale: triu = 4*S - Tt
            float l = (4.0f * S - Tt) / Tt;
            out[0] = l * l;
        }
    }
}

extern "C" void kernel_launch(void* const* d_in, const int* in_sizes, int n_in,
                              void* d_out, int out_size, void* d_ws, size_t ws_size,
                              hipStream_t stream) {
    const float* pos = (const float*)d_in[0];
    const float* msx = (const float*)d_in[1];
    const float* msy = (const float*)d_in[2];
    const float* bpx = (const float*)d_in[3];
    const float* bpy = (const float*)d_in[4];
    const int*  midx = (const int*)d_in[5];

    const int num_nodes = in_sizes[0] / 2;
    const int m  = in_sizes[5];          // 4000 movable macros
    const int nb = in_sizes[3];          // 252 boundary nodes
    const int N  = m + nb;

    const int T    = (N + TI - 1) / TI;  // 68 tiles
    const int nblk = T * (T + 1) / 2;    // 2346 triangular tile-pairs

    float*    S_accum = (float*)d_ws;
    float*    T_accum = S_accum + 1;
    unsigned* done    = (unsigned*)(S_accum + 2);

    hipMemsetAsync(d_ws, 0, 16, stream);   // zero S, T, done each call

    fused_kernel<<<nblk, BT, 0, stream>>>(pos, msx, msy, bpx, bpy, midx,
                                          num_nodes, m, N, T, nblk,
                                          S_accum, T_accum, done,
                                          (float*)d_out);
}